// Round 2
// baseline (466.195 us; speedup 1.0000x reference)
//
#include <hip/hip_runtime.h>
#include <hip/hip_bf16.h>

#define NPTS 1048576
#define NCLU 16384
#define DF   64
#define H1   128
#define H2   64
#define BP   64                      // points per tile
#define NBLK 768                     // persistent blocks (3 per CU exactly)
#define NTILES (NPTS / BP)           // 16384 tiles, grid-stride
#define K1P  104                     // LDS row stride (u16) for K=96 (67 valid + bias@67 + zero pad)
#define K2P  136                     // LDS row stride (u16) for K=128

typedef __bf16 bf16x8 __attribute__((ext_vector_type(8)));
typedef __bf16 bf16x4 __attribute__((ext_vector_type(4)));
typedef float  f32x4  __attribute__((ext_vector_type(4)));
typedef unsigned short u16x4 __attribute__((ext_vector_type(4)));
typedef unsigned short u16x8 __attribute__((ext_vector_type(8)));

__device__ __forceinline__ unsigned short f2b(float f) {
  unsigned v; __builtin_memcpy(&v, &f, 4);
  v += 0x7fffu + ((v >> 16) & 1u);          // round-to-nearest-even
  return (unsigned short)(v >> 16);
}

// pre-kernel: feat fp32 [16384][64] -> bf16 u16 same layout in ws
__global__ __launch_bounds__(256, 4)
void cvt_feat(const float* __restrict__ f, unsigned short* __restrict__ o) {
  int i = (blockIdx.x * 256 + threadIdx.x) * 4;
  f32x4 v = *(const f32x4*)&f[i];
  u16x4 h;
  #pragma unroll
  for (int j = 0; j < 4; ++j) h[j] = f2b(v[j]);
  *(u16x4*)&o[i] = h;
}

// Swapped-operand structure:
//   GEMM1: acc1[nt] = mfma(W1frag, Xfrag)  -> lane holds h[m=l16][n = nt*16+quad*4+r]
//   epilogue1: relu + bf16 -> 8x ds_write_b64 (4 contiguous k per lane)
//   GEMM2: acc2[nt2] = mfma(W2frag(regs), Hfrag) -> lane holds out[m=l16][n2 = nt2*16+quad*4+r]
//   store: 4x global_store_dwordx4 per lane-tile, fully coalesced
// b1 folded into W1 via constant-1 input at k=67; b2 via accumulator init.
__global__ __launch_bounds__(256, 3)
void fused_gather_mlp(const float* __restrict__ feat,
                      const int* __restrict__ labels,
                      const float* __restrict__ centers,
                      const float* __restrict__ points,
                      const float* __restrict__ W1,
                      const float* __restrict__ b1,
                      const float* __restrict__ W2,
                      const float* __restrict__ b2,
                      float* __restrict__ out,
                      const unsigned short* __restrict__ featbf,
                      int use_bf)
{
  __shared__ __align__(16) unsigned short sW1[H1][K1P];  // W1^T bf16 [n][k], bias row at k=67
  __shared__ __align__(16) unsigned short sH[BP][K2P];   // hidden bf16 (wave-private rows)

  const int t    = threadIdx.x;
  const int w    = t >> 6;
  const int lane = t & 63;
  const int quad = lane >> 4, l16 = lane & 15;
  const int m0   = w * 16;                 // this wave's 16-row M tile

  // ---------------- one-time staging ----------------
  // W1 [67][128] (+ b1 as row 67) -> sW1[n][k]
  #pragma unroll
  for (int i = 0; i < 6; ++i) {            // 128 n * 12 kc = 1536 tasks
    int task = t + 256 * i;
    int n = task & 127, kc = task >> 7;
    u16x8 h;
    #pragma unroll
    for (int j = 0; j < 8; ++j) {
      int k = kc * 8 + j;
      float v = (k < 67) ? W1[k * H1 + n] : ((k == 67) ? b1[n] : 0.f);
      h[j] = f2b(v);
    }
    *(u16x8*)&sW1[n][kc * 8] = h;
  }

  // W2 -> per-lane register fragments (loop-invariant). Lane (quad,l16) holds
  // W2^T row nt2*16+l16, k = ks*32+quad*8 .. +8.
  bf16x8 w2f[4][4];
  #pragma unroll
  for (int nt2 = 0; nt2 < 4; ++nt2) {
    #pragma unroll
    for (int ks = 0; ks < 4; ++ks) {
      #pragma unroll
      for (int j = 0; j < 8; ++j)
        w2f[nt2][ks][j] = (__bf16)W2[(ks * 32 + quad * 8 + j) * H2 + (nt2 * 16 + l16)];
    }
  }
  // bias2 as accumulator-init: acc2[nt2][r] corresponds to n2 = nt2*16+quad*4+r
  f32x4 bias2v[4];
  #pragma unroll
  for (int nt2 = 0; nt2 < 4; ++nt2)
    bias2v[nt2] = *(const f32x4*)&b2[nt2 * 16 + quad * 4];

  __syncthreads();                         // the ONLY barrier

  // ---------------- main loop: grid-stride tiles, all wave-private ----------------
  for (int tile = blockIdx.x; tile < NTILES; tile += NBLK) {
    const int p0  = tile * BP;
    const int p   = p0 + m0 + l16;         // this lane's point row (quads duplicate)
    const int lab = labels[p];

    // X fragments direct from global (L2-resident bf16 table), zero redundancy:
    // lane (quad,l16) holds X row l16, k = quad*8 (ks=0) and 32+quad*8 (ks=1)
    bf16x8 ax0, ax1;
    if (use_bf) {
      ax0 = *(const bf16x8*)&featbf[(long)lab * DF + quad * 8];
      ax1 = *(const bf16x8*)&featbf[(long)lab * DF + 32 + quad * 8];
    } else {
      f32x4 v0 = *(const f32x4*)&feat[(long)lab * DF + quad * 8];
      f32x4 v1 = *(const f32x4*)&feat[(long)lab * DF + quad * 8 + 4];
      f32x4 v2 = *(const f32x4*)&feat[(long)lab * DF + 32 + quad * 8];
      f32x4 v3 = *(const f32x4*)&feat[(long)lab * DF + 32 + quad * 8 + 4];
      #pragma unroll
      for (int j = 0; j < 4; ++j) {
        ax0[j] = (__bf16)v0[j]; ax0[j + 4] = (__bf16)v1[j];
        ax1[j] = (__bf16)v2[j]; ax1[j + 4] = (__bf16)v3[j];
      }
    }
    // ks=2 fragment: k=64..95. quad0 holds k 64..71: [d0,d1,d2, 1.0(bias), 0,0,0,0];
    // quads 1..3 are the zero pad (W1 rows are zero there too).
    bf16x8 a2;
    #pragma unroll
    for (int j = 0; j < 8; ++j) a2[j] = (__bf16)0.0f;
    if (quad == 0) {
      float d0 = centers[lab * 3 + 0] - points[(long)p * 3 + 0];
      float d1 = centers[lab * 3 + 1] - points[(long)p * 3 + 1];
      float d2 = centers[lab * 3 + 2] - points[(long)p * 3 + 2];
      a2[0] = (__bf16)d0; a2[1] = (__bf16)d1; a2[2] = (__bf16)d2;
      a2[3] = (__bf16)1.0f;                // bias-1 input
    }

    // GEMM1 (swapped): [128n x 96k] . [16m x 96k]^T
    f32x4 acc1[8];
    #pragma unroll
    for (int i = 0; i < 8; ++i) acc1[i] = (f32x4){0.f, 0.f, 0.f, 0.f};
    #pragma unroll
    for (int nt = 0; nt < 8; ++nt) {
      bf16x8 wa = *(const bf16x8*)&sW1[nt * 16 + l16][quad * 8];
      bf16x8 wb = *(const bf16x8*)&sW1[nt * 16 + l16][32 + quad * 8];
      bf16x8 wc = *(const bf16x8*)&sW1[nt * 16 + l16][64 + quad * 8];
      acc1[nt] = __builtin_amdgcn_mfma_f32_16x16x32_bf16(wa, ax0, acc1[nt], 0, 0, 0);
      acc1[nt] = __builtin_amdgcn_mfma_f32_16x16x32_bf16(wb, ax1, acc1[nt], 0, 0, 0);
      acc1[nt] = __builtin_amdgcn_mfma_f32_16x16x32_bf16(wc, a2,  acc1[nt], 0, 0, 0);
    }
    // epilogue 1: relu -> bf16 -> sH[m=l16][nt*16+quad*4 .. +4] (b64 writes, wave-private)
    #pragma unroll
    for (int nt = 0; nt < 8; ++nt) {
      bf16x4 hv;
      #pragma unroll
      for (int r = 0; r < 4; ++r) {
        float v = acc1[nt][r];
        hv[r] = (__bf16)(v > 0.f ? v : 0.f);
      }
      *(bf16x4*)&sH[m0 + l16][nt * 16 + quad * 4] = hv;
    }

    // GEMM2 (swapped): [64n2 x 128k] . [16m x 128k]^T, W2 from registers
    f32x4 acc2[4];
    #pragma unroll
    for (int i = 0; i < 4; ++i) acc2[i] = bias2v[i];
    #pragma unroll
    for (int ks = 0; ks < 4; ++ks) {
      bf16x8 hf = *(const bf16x8*)&sH[m0 + l16][ks * 32 + quad * 8];
      #pragma unroll
      for (int nt2 = 0; nt2 < 4; ++nt2)
        acc2[nt2] = __builtin_amdgcn_mfma_f32_16x16x32_bf16(w2f[nt2][ks], hf, acc2[nt2], 0, 0, 0);
    }
    // epilogue 2: relu -> coalesced float4 stores (lane owns row l16, 4 contiguous n2)
    #pragma unroll
    for (int nt2 = 0; nt2 < 4; ++nt2) {
      f32x4 v = acc2[nt2];
      #pragma unroll
      for (int r = 0; r < 4; ++r) v[r] = v[r] > 0.f ? v[r] : 0.f;
      *(f32x4*)&out[(long)p * H2 + nt2 * 16 + quad * 4] = v;
    }
  }
}

extern "C" void kernel_launch(void* const* d_in, const int* in_sizes, int n_in,
                              void* d_out, int out_size, void* d_ws, size_t ws_size,
                              hipStream_t stream) {
  const float* feat   = (const float*)d_in[0];
  const int*   labels = (const int*)d_in[1];
  const float* cen    = (const float*)d_in[2];
  const float* pts    = (const float*)d_in[3];
  const float* W1     = (const float*)d_in[4];
  const float* b1     = (const float*)d_in[5];
  const float* W2     = (const float*)d_in[6];
  const float* b2     = (const float*)d_in[7];
  float*       outp   = (float*)d_out;

  const size_t featbf_bytes = (size_t)NCLU * DF * sizeof(unsigned short);  // 2 MB
  int use_bf = (ws_size >= featbf_bytes) ? 1 : 0;
  unsigned short* featbf = (unsigned short*)d_ws;

  if (use_bf)
    cvt_feat<<<dim3(NCLU * DF / (256 * 4)), dim3(256), 0, stream>>>(feat, featbf);

  fused_gather_mlp<<<dim3(NBLK), dim3(256), 0, stream>>>(
      feat, labels, cen, pts, W1, b1, W2, b2, outp, featbf, use_bf);
}